// Round 4
// baseline (474.061 us; speedup 1.0000x reference)
//
#include <hip/hip_runtime.h>
#include <hip/hip_fp16.h>

// MoE B=2,N=2048,C=1024,F=4096,E=8,K=2 (T=4096, slots=8192)
// Pre-packed swizzled 128x64 fp16 tiles -> linear global_load_lds staging.
// GEMM K-loop: double-buffered LDS, prefetch-before-compute, counted vmcnt,
// raw s_barrier (loads stay in flight across barriers). XCD-swizzled grids.

#define T_TOK 4096
#define C_DIM 1024
#define F_DIM 4096
#define E_NUM 8
#define BM 128
#define BN 128
#define BK 64
#define MAXT 72            // max global row-tiles: 8192/128 + 7 pad
#define TILE_H 8192        // halfs per 128x64 tile (16KB)

typedef float f32x4 __attribute__((ext_vector_type(4)));
typedef _Float16 half8 __attribute__((ext_vector_type(8)));

#define AS1 __attribute__((address_space(1)))
#define AS3 __attribute__((address_space(3)))

__device__ __forceinline__ int swz(int r, int ec) { return ec ^ ((r & 7) << 3); }

__device__ __forceinline__ half8 cvt8(float4 f0, float4 f1) {
  half8 hv;
  hv[0] = (_Float16)f0.x; hv[1] = (_Float16)f0.y; hv[2] = (_Float16)f0.z; hv[3] = (_Float16)f0.w;
  hv[4] = (_Float16)f1.x; hv[5] = (_Float16)f1.y; hv[6] = (_Float16)f1.z; hv[7] = (_Float16)f1.w;
  return hv;
}

// bijective XCD chunk swizzle (m204)
__device__ __forceinline__ int xcd_swz(int bid, int nwg) {
  int xcd = bid & 7, rest = bid >> 3;
  int q = nwg >> 3, r = nwg & 7;
  return (xcd < r ? xcd * (q + 1) : r * (q + 1) + (xcd - r) * q) + rest;
}

// ---------------- Router
__global__ __launch_bounds__(256) void router_kernel(
    const float* __restrict__ x, const float* __restrict__ rw,
    int* __restrict__ top_idx, float* __restrict__ top_w)
{
  int t = blockIdx.x * 4 + (threadIdx.x >> 6);
  int lane = threadIdx.x & 63;
  const float* xr = x + (size_t)t * C_DIM;
  float acc[E_NUM];
#pragma unroll
  for (int e = 0; e < E_NUM; ++e) acc[e] = 0.f;
  for (int j = 0; j < C_DIM / 64; ++j) {
    int c = j * 64 + lane;
    float xv = xr[c];
#pragma unroll
    for (int e = 0; e < E_NUM; ++e) acc[e] += xv * rw[e * C_DIM + c];
  }
#pragma unroll
  for (int e = 0; e < E_NUM; ++e) {
    float v = acc[e];
#pragma unroll
    for (int off = 32; off > 0; off >>= 1) v += __shfl_xor(v, off);
    acc[e] = v;
  }
  if (lane == 0) {
    float mx = acc[0];
    for (int e = 1; e < E_NUM; ++e) mx = fmaxf(mx, acc[e]);
    float p[E_NUM]; float Z = 0.f;
    for (int e = 0; e < E_NUM; ++e) { p[e] = expf(acc[e] - mx); Z += p[e]; }
    int b0 = 0;
    for (int e = 1; e < E_NUM; ++e) if (p[e] > p[b0]) b0 = e;
    int b1i = -1; float pb = -1.f;
    for (int e = 0; e < E_NUM; ++e) if (e != b0 && p[e] > pb) { pb = p[e]; b1i = e; }
    float p0 = p[b0] / Z, p1 = pb / Z;
    float s = p0 + p1 + 1e-9f;
    top_idx[t * 2 + 0] = b0;
    top_idx[t * 2 + 1] = b1i;
    top_w[t * 2 + 0] = p0 / s;
    top_w[t * 2 + 1] = p1 / s;
  }
}

// ---------------- Lists
__global__ void build_lists(const int* __restrict__ top_idx,
                            int* __restrict__ rows_g, int* __restrict__ counts,
                            int* __restrict__ tile_off)
{
  int e = threadIdx.x >> 6;
  int lane = threadIdx.x & 63;
  int cnt = 0;
  for (int t0 = 0; t0 < T_TOK; t0 += 64) {
    int t = t0 + lane;
    bool sel = (top_idx[t * 2] == e) || (top_idx[t * 2 + 1] == e);
    cnt += __popcll(__ballot(sel));
  }
  if (lane == 0) counts[e] = cnt;
  __syncthreads();
  if (threadIdx.x == 0) {
    int o = 0;
    for (int i = 0; i < E_NUM; ++i) { tile_off[i] = o; o += (counts[i] + BM - 1) / BM; }
    tile_off[E_NUM] = o;
  }
  __syncthreads();
  int base = tile_off[e] * BM;
  int pos = 0;
  for (int t0 = 0; t0 < T_TOK; t0 += 64) {
    int t = t0 + lane;
    int i0 = top_idx[t * 2], i1 = top_idx[t * 2 + 1];
    bool sel = (i0 == e) || (i1 == e);
    unsigned long long mask = __ballot(sel);
    if (sel) {
      int p = pos + __popcll(mask & ((1ull << lane) - 1ull));
      rows_g[base + p] = t * 2 + ((i0 == e) ? 0 : 1);
    }
    pos += __popcll(mask);
  }
}

// ---------------- Gather x -> tiled swizzled fp16
__global__ __launch_bounds__(256) void gather_x(
    const float* __restrict__ x, const int* __restrict__ rows_g,
    const int* __restrict__ counts, const int* __restrict__ tile_off,
    _Float16* __restrict__ xg)
{
  unsigned g = blockIdx.x * 256 + threadIdx.x;
  unsigned p = g >> 7, ccr = g & 127;
  int gt = p >> 7, r = p & 127;
  int kc = ccr >> 3, c8 = ccr & 7;
  int e = -1;
#pragma unroll
  for (int i = 0; i < E_NUM; ++i)
    if (gt >= tile_off[i] && gt < tile_off[i + 1]) e = i;
  half8 hv = {};
  if (e >= 0) {
    int nrem = counts[e] - (gt - tile_off[e]) * BM;
    if (r < nrem) {
      int t = rows_g[p] >> 1;
      const float4* s = reinterpret_cast<const float4*>(x + (size_t)t * C_DIM + kc * 64 + c8 * 8);
      hv = cvt8(s[0], s[1]);
    }
  }
  *reinterpret_cast<half8*>(xg + ((size_t)gt * 16 + kc) * TILE_H + r * 64 + ((c8 ^ (r & 7)) << 3)) = hv;
}

// ---------------- w1 -> tiled fp16
__global__ __launch_bounds__(256) void cvt_w1(
    const float* __restrict__ src, _Float16* __restrict__ dst, int ch, int Fc, int lgFc)
{
  unsigned g = blockIdx.x * 256 + threadIdx.x;
  unsigned row = g >> 7, ccr = g & 127;
  int e = row >> lgFc, frow = row & (Fc - 1);
  int ftl = frow >> 7, r = frow & 127;
  int kc = ccr >> 3, c8 = ccr & 7;
  const float4* s = reinterpret_cast<const float4*>(
      src + ((size_t)e * F_DIM + ch * Fc + frow) * C_DIM + kc * 64 + c8 * 8);
  int nft = Fc >> 7;
  size_t tix = ((size_t)(e * nft + ftl) * 16 + kc);
  *reinterpret_cast<half8*>(dst + tix * TILE_H + r * 64 + ((c8 ^ (r & 7)) << 3)) = cvt8(s[0], s[1]);
}

// ---------------- w2 -> tiled fp16
__global__ __launch_bounds__(256) void cvt_w2(
    const float* __restrict__ src, _Float16* __restrict__ dst, int ch, int Fc, int lgc)
{
  unsigned g = blockIdx.x * 256 + threadIdx.x;
  unsigned row = g >> lgc, ccr = g & ((Fc >> 3) - 1);
  int e = row >> 10, c = row & 1023;
  int ct = c >> 7, r = c & 127;
  int kc = ccr >> 3, c8 = ccr & 7;
  const float4* s = reinterpret_cast<const float4*>(
      src + (size_t)row * F_DIM + ch * Fc + kc * 64 + c8 * 8);
  int nkc = Fc >> 6;
  size_t tix = ((size_t)(e * 8 + ct) * nkc + kc);
  *reinterpret_cast<half8*>(dst + tix * TILE_H + r * 64 + ((c8 ^ (r & 7)) << 3)) = cvt8(s[0], s[1]);
}

// ======== shared GEMM pieces: dbuf staging + compute on one buffer ========
#define STAGE_TILE(At_, Bt_, kc_, buf_)                                           \
  {                                                                               \
    const _Float16* a_ = (At_) + (size_t)(kc_) * TILE_H + wave * 2048 + lane * 8; \
    const _Float16* b_ = (Bt_) + (size_t)(kc_) * TILE_H + wave * 2048 + lane * 8; \
    _Pragma("unroll")                                                             \
    for (int c_ = 0; c_ < 4; ++c_) {                                              \
      __builtin_amdgcn_global_load_lds((const AS1 void*)(a_ + c_ * 512),          \
          (AS3 void*)(&As[buf_][(wave * 4 + c_) * 512]), 16, 0, 0);               \
      __builtin_amdgcn_global_load_lds((const AS1 void*)(b_ + c_ * 512),          \
          (AS3 void*)(&Bs[buf_][(wave * 4 + c_) * 512]), 16, 0, 0);               \
    }                                                                             \
  }

#define COMPUTE_TILE(buf_)                                                        \
  _Pragma("unroll")                                                               \
  for (int kk = 0; kk < BK; kk += 32) {                                           \
    const int klo = kk + (lane >> 4) * 8;                                         \
    half8 aF[4], bF[4];                                                           \
    _Pragma("unroll")                                                             \
    for (int m = 0; m < 4; ++m) {                                                 \
      int r = wr * 64 + m * 16 + (lane & 15);                                     \
      aF[m] = *reinterpret_cast<const half8*>(&As[buf_][r * BK + swz(r, klo)]);   \
    }                                                                             \
    _Pragma("unroll")                                                             \
    for (int n = 0; n < 4; ++n) {                                                 \
      int r = wc * 64 + n * 16 + (lane & 15);                                     \
      bF[n] = *reinterpret_cast<const half8*>(&Bs[buf_][r * BK + swz(r, klo)]);   \
    }                                                                             \
    _Pragma("unroll")                                                             \
    for (int m = 0; m < 4; ++m)                                                   \
      _Pragma("unroll")                                                           \
      for (int n = 0; n < 4; ++n)                                                 \
        acc[m][n] = __builtin_amdgcn_mfma_f32_16x16x32_f16(aF[m], bF[n], acc[m][n], 0, 0, 0); \
  }

// ---------------- GEMM1: ht[pos, f] = relu(xg[pos] . w1t[e][f] + b1)
__global__ __launch_bounds__(256) void gemm1_kernel(
    const _Float16* __restrict__ xg, const _Float16* __restrict__ w1t,
    const float* __restrict__ b1, const int* __restrict__ counts,
    const int* __restrict__ tile_off, _Float16* __restrict__ ht,
    int ch, int Fc)
{
  const int wgid = xcd_swz(blockIdx.x, gridDim.x);
  const int ft = wgid / MAXT;
  const int gt = wgid - ft * MAXT;
  if (gt >= tile_off[E_NUM]) return;
  int e = 0;
  while (gt >= tile_off[e + 1]) ++e;
  const int nrem = min(counts[e] - (gt - tile_off[e]) * BM, BM);
  const int nft = Fc >> 7;
  const _Float16* At = xg + (size_t)gt * 16 * TILE_H;
  const _Float16* Bt = w1t + (size_t)(e * nft + ft) * 16 * TILE_H;

  __shared__ __align__(16) _Float16 As[2][TILE_H];
  __shared__ __align__(16) _Float16 Bs[2][TILE_H];

  const int tid = threadIdx.x;
  const int lane = tid & 63;
  const int wave = tid >> 6;
  const int wr = wave >> 1, wc = wave & 1;

  f32x4 acc[4][4];
#pragma unroll
  for (int m = 0; m < 4; ++m)
#pragma unroll
    for (int n = 0; n < 4; ++n) acc[m][n] = (f32x4){0.f, 0.f, 0.f, 0.f};

  STAGE_TILE(At, Bt, 0, 0);
  int cur = 0;
  for (int kc = 0; kc < 16; ++kc) {
    if (kc + 1 < 16) {
      STAGE_TILE(At, Bt, kc + 1, cur ^ 1);
      asm volatile("s_waitcnt vmcnt(8)" ::: "memory");
    } else {
      asm volatile("s_waitcnt vmcnt(0)" ::: "memory");
    }
    __builtin_amdgcn_sched_barrier(0);
    __builtin_amdgcn_s_barrier();
    __builtin_amdgcn_sched_barrier(0);
    COMPUTE_TILE(cur);
    __builtin_amdgcn_sched_barrier(0);
    __builtin_amdgcn_s_barrier();
    cur ^= 1;
  }

  const int nkcF = Fc >> 6;
#pragma unroll
  for (int m = 0; m < 4; ++m) {
#pragma unroll
    for (int j = 0; j < 4; ++j) {
      int iloc = wr * 64 + m * 16 + (lane >> 4) * 4 + j;
      if (iloc < nrem) {
#pragma unroll
        for (int n = 0; n < 4; ++n) {
          int fl = ft * BN + wc * 64 + n * 16 + (lane & 15);
          float v = acc[m][n][j] + b1[e * F_DIM + ch * Fc + fl];
          _Float16 h = (_Float16)fmaxf(v, 0.f);
          ht[((size_t)gt * nkcF + (fl >> 6)) * TILE_H + iloc * 64 +
             ((((fl >> 3) & 7) ^ (iloc & 7)) << 3) + (fl & 7)] = h;
        }
      }
    }
  }
}

// ---------------- GEMM2: out[t] += top_w * (ht[pos] . w2t[e][c] + b2)
__global__ __launch_bounds__(256) void gemm2_kernel(
    const _Float16* __restrict__ ht, const _Float16* __restrict__ w2t,
    const float* __restrict__ b2, const int* __restrict__ rows_g,
    const int* __restrict__ counts, const int* __restrict__ tile_off,
    const float* __restrict__ top_w, float* __restrict__ out,
    int Fc, int kspl, int add_bias)
{
  const int wgid = xcd_swz(blockIdx.x, gridDim.x);
  const int ctks = wgid / MAXT;
  const int gt = wgid - ctks * MAXT;
  if (gt >= tile_off[E_NUM]) return;
  const int ct = ctks & 7;
  const int ks = ctks >> 3;
  int e = 0;
  while (gt >= tile_off[e + 1]) ++e;
  const int nrem = min(counts[e] - (gt - tile_off[e]) * BM, BM);
  const int nkc = Fc >> 6;
  const int klen = nkc / kspl;
  const _Float16* At = ht + ((size_t)gt * nkc + ks * klen) * TILE_H;
  const _Float16* Bt = w2t + ((size_t)(e * 8 + ct) * nkc + ks * klen) * TILE_H;

  __shared__ __align__(16) _Float16 As[2][TILE_H];
  __shared__ __align__(16) _Float16 Bs[2][TILE_H];

  const int tid = threadIdx.x;
  const int lane = tid & 63;
  const int wave = tid >> 6;
  const int wr = wave >> 1, wc = wave & 1;

  f32x4 acc[4][4];
#pragma unroll
  for (int m = 0; m < 4; ++m)
#pragma unroll
    for (int n = 0; n < 4; ++n) acc[m][n] = (f32x4){0.f, 0.f, 0.f, 0.f};

  STAGE_TILE(At, Bt, 0, 0);
  int cur = 0;
  for (int kc = 0; kc < klen; ++kc) {
    if (kc + 1 < klen) {
      STAGE_TILE(At, Bt, kc + 1, cur ^ 1);
      asm volatile("s_waitcnt vmcnt(8)" ::: "memory");
    } else {
      asm volatile("s_waitcnt vmcnt(0)" ::: "memory");
    }
    __builtin_amdgcn_sched_barrier(0);
    __builtin_amdgcn_s_barrier();
    __builtin_amdgcn_sched_barrier(0);
    COMPUTE_TILE(cur);
    __builtin_amdgcn_sched_barrier(0);
    __builtin_amdgcn_s_barrier();
    cur ^= 1;
  }

#pragma unroll
  for (int m = 0; m < 4; ++m) {
#pragma unroll
    for (int j = 0; j < 4; ++j) {
      int iloc = wr * 64 + m * 16 + (lane >> 4) * 4 + j;
      if (iloc < nrem) {
        int slot = rows_g[gt * BM + iloc];
        int t = slot >> 1;
        float wgt = top_w[slot];
#pragma unroll
        for (int n = 0; n < 4; ++n) {
          int c = ct * BN + wc * 64 + n * 16 + (lane & 15);
          float v = acc[m][n][j];
          if (add_bias && ks == 0) v += b2[e * C_DIM + c];
          atomicAdd(out + (size_t)t * C_DIM + c, wgt * v);
        }
      }
    }
  }
}

extern "C" void kernel_launch(void* const* d_in, const int* in_sizes, int n_in,
                              void* d_out, int out_size, void* d_ws, size_t ws_size,
                              hipStream_t stream)
{
  const float* x  = (const float*)d_in[0];
  const float* rw = (const float*)d_in[1];
  const float* w1 = (const float*)d_in[2];
  const float* b1 = (const float*)d_in[3];
  const float* w2 = (const float*)d_in[4];
  const float* b2 = (const float*)d_in[5];
  float* out = (float*)d_out;

  char* ws = (char*)d_ws;
  size_t off = 0;
  auto carve = [&](size_t bytes) -> void* {
    void* p = ws + off;
    off += (bytes + 255) & ~(size_t)255;
    return p;
  };
  int*   top_idx  = (int*)carve((size_t)T_TOK * 2 * sizeof(int));
  float* top_w    = (float*)carve((size_t)T_TOK * 2 * sizeof(float));
  int*   counts   = (int*)carve(E_NUM * sizeof(int));
  int*   tile_off = (int*)carve((E_NUM + 1) * sizeof(int));
  int*   rows_g   = (int*)carve((size_t)MAXT * BM * sizeof(int));
  _Float16* xg    = (_Float16*)carve((size_t)MAXT * 16 * TILE_H * sizeof(_Float16));
  size_t fixed = off;

  int nchunk = 8;
  const int cands[4] = {1, 2, 4, 8};
  for (int ci = 0; ci < 4; ++ci) {
    int n = cands[ci];
    size_t fc = (size_t)(F_DIM / n);
    size_t w1b = ((size_t)E_NUM * fc * C_DIM * 2 + 255) & ~(size_t)255;
    size_t w2b = ((size_t)E_NUM * C_DIM * fc * 2 + 255) & ~(size_t)255;
    size_t htb = ((size_t)MAXT * (fc >> 6) * TILE_H * 2 + 255) & ~(size_t)255;
    if (fixed + w1b + w2b + htb <= ws_size) { nchunk = n; break; }
  }
  const int Fc = F_DIM / nchunk;
  int lgFc = 0; while ((1 << lgFc) < Fc) ++lgFc;
  _Float16* w1t = (_Float16*)carve((size_t)E_NUM * Fc * C_DIM * sizeof(_Float16));
  _Float16* w2t = (_Float16*)carve((size_t)E_NUM * C_DIM * Fc * sizeof(_Float16));
  _Float16* ht  = (_Float16*)carve((size_t)MAXT * (Fc >> 6) * TILE_H * sizeof(_Float16));

  const int kspl = (Fc >= 2048) ? 2 : 1;

  hipMemsetAsync(out, 0, (size_t)out_size * sizeof(float), stream);
  router_kernel<<<T_TOK / 4, 256, 0, stream>>>(x, rw, top_idx, top_w);
  build_lists<<<1, 512, 0, stream>>>(top_idx, rows_g, counts, tile_off);
  gather_x<<<(MAXT * BM * 128) / 256, 256, 0, stream>>>(x, rows_g, counts, tile_off, xg);

  const int cvt_blocks = 4 * Fc;
  for (int ch = 0; ch < nchunk; ++ch) {
    cvt_w1<<<cvt_blocks, 256, 0, stream>>>(w1, w1t, ch, Fc, lgFc);
    cvt_w2<<<cvt_blocks, 256, 0, stream>>>(w2, w2t, ch, Fc, lgFc - 3);
    gemm1_kernel<<<MAXT * (Fc / BN), 256, 0, stream>>>(
        xg, w1t, b1, counts, tile_off, ht, ch, Fc);
    gemm2_kernel<<<MAXT * 8 * kspl, 256, 0, stream>>>(
        ht, w2t, b2, rows_g, counts, tile_off, top_w, out, Fc, kspl, ch == 0);
  }
}

// Round 5
// 381.983 us; speedup vs baseline: 1.2411x; 1.2411x over previous
//
#include <hip/hip_runtime.h>
#include <hip/hip_fp16.h>

// MoE B=2,N=2048,C=1024,F=4096,E=8,K=2 (T=4096, slots=8192)
// Pre-packed swizzled 128x64 fp16 tiles -> linear global_load_lds staging.
// Serial single-buffer K-loop (proven r3; dbuf regressed occupancy in r4).
// gemm2 writes fp16 partials to y (no atomics); combine kernel does the
// weighted slot sum + bias with coalesced traffic.

#define T_TOK 4096
#define C_DIM 1024
#define F_DIM 4096
#define E_NUM 8
#define BM 128
#define BN 128
#define BK 64
#define MAXT 72            // max global row-tiles: 8192/128 + 7 pad
#define NP   (MAXT * BM)   // padded positions
#define TILE_H 8192        // halfs per 128x64 tile (16KB)

typedef float f32x4 __attribute__((ext_vector_type(4)));
typedef _Float16 half8 __attribute__((ext_vector_type(8)));

#define AS1 __attribute__((address_space(1)))
#define AS3 __attribute__((address_space(3)))

__device__ __forceinline__ int swz(int r, int ec) { return ec ^ ((r & 7) << 3); }

__device__ __forceinline__ half8 cvt8(float4 f0, float4 f1) {
  half8 hv;
  hv[0] = (_Float16)f0.x; hv[1] = (_Float16)f0.y; hv[2] = (_Float16)f0.z; hv[3] = (_Float16)f0.w;
  hv[4] = (_Float16)f1.x; hv[5] = (_Float16)f1.y; hv[6] = (_Float16)f1.z; hv[7] = (_Float16)f1.w;
  return hv;
}

// bijective XCD chunk swizzle (m204)
__device__ __forceinline__ int xcd_swz(int bid, int nwg) {
  int xcd = bid & 7, rest = bid >> 3;
  int q = nwg >> 3, r = nwg & 7;
  return (xcd < r ? xcd * (q + 1) : r * (q + 1) + (xcd - r) * q) + rest;
}

// ---------------- Router
__global__ __launch_bounds__(256) void router_kernel(
    const float* __restrict__ x, const float* __restrict__ rw,
    int* __restrict__ top_idx, float* __restrict__ top_w)
{
  int t = blockIdx.x * 4 + (threadIdx.x >> 6);
  int lane = threadIdx.x & 63;
  const float* xr = x + (size_t)t * C_DIM;
  float acc[E_NUM];
#pragma unroll
  for (int e = 0; e < E_NUM; ++e) acc[e] = 0.f;
  for (int j = 0; j < C_DIM / 64; ++j) {
    int c = j * 64 + lane;
    float xv = xr[c];
#pragma unroll
    for (int e = 0; e < E_NUM; ++e) acc[e] += xv * rw[e * C_DIM + c];
  }
#pragma unroll
  for (int e = 0; e < E_NUM; ++e) {
    float v = acc[e];
#pragma unroll
    for (int off = 32; off > 0; off >>= 1) v += __shfl_xor(v, off);
    acc[e] = v;
  }
  if (lane == 0) {
    float mx = acc[0];
    for (int e = 1; e < E_NUM; ++e) mx = fmaxf(mx, acc[e]);
    float p[E_NUM]; float Z = 0.f;
    for (int e = 0; e < E_NUM; ++e) { p[e] = expf(acc[e] - mx); Z += p[e]; }
    int b0 = 0;
    for (int e = 1; e < E_NUM; ++e) if (p[e] > p[b0]) b0 = e;
    int b1i = -1; float pb = -1.f;
    for (int e = 0; e < E_NUM; ++e) if (e != b0 && p[e] > pb) { pb = p[e]; b1i = e; }
    float p0 = p[b0] / Z, p1 = pb / Z;
    float s = p0 + p1 + 1e-9f;
    top_idx[t * 2 + 0] = b0;
    top_idx[t * 2 + 1] = b1i;
    top_w[t * 2 + 0] = p0 / s;
    top_w[t * 2 + 1] = p1 / s;
  }
}

// ---------------- Lists (+ inverse map slot -> (expert, padded position))
__global__ void build_lists(const int* __restrict__ top_idx,
                            int* __restrict__ rows_g, int* __restrict__ counts,
                            int* __restrict__ tile_off, int* __restrict__ inv)
{
  int e = threadIdx.x >> 6;
  int lane = threadIdx.x & 63;
  int cnt = 0;
  for (int t0 = 0; t0 < T_TOK; t0 += 64) {
    int t = t0 + lane;
    bool sel = (top_idx[t * 2] == e) || (top_idx[t * 2 + 1] == e);
    cnt += __popcll(__ballot(sel));
  }
  if (lane == 0) counts[e] = cnt;
  __syncthreads();
  if (threadIdx.x == 0) {
    int o = 0;
    for (int i = 0; i < E_NUM; ++i) { tile_off[i] = o; o += (counts[i] + BM - 1) / BM; }
    tile_off[E_NUM] = o;
  }
  __syncthreads();
  int base = tile_off[e] * BM;
  int pos = 0;
  for (int t0 = 0; t0 < T_TOK; t0 += 64) {
    int t = t0 + lane;
    int i0 = top_idx[t * 2], i1 = top_idx[t * 2 + 1];
    bool sel = (i0 == e) || (i1 == e);
    unsigned long long mask = __ballot(sel);
    if (sel) {
      int p = pos + __popcll(mask & ((1ull << lane) - 1ull));
      int slot = t * 2 + ((i0 == e) ? 0 : 1);
      rows_g[base + p] = slot;
      inv[slot] = (e << 16) | (base + p);
    }
    pos += __popcll(mask);
  }
}

// ---------------- Gather x -> tiled swizzled fp16
__global__ __launch_bounds__(256) void gather_x(
    const float* __restrict__ x, const int* __restrict__ rows_g,
    const int* __restrict__ counts, const int* __restrict__ tile_off,
    _Float16* __restrict__ xg)
{
  unsigned g = blockIdx.x * 256 + threadIdx.x;
  unsigned p = g >> 7, ccr = g & 127;
  int gt = p >> 7, r = p & 127;
  int kc = ccr >> 3, c8 = ccr & 7;
  int e = -1;
#pragma unroll
  for (int i = 0; i < E_NUM; ++i)
    if (gt >= tile_off[i] && gt < tile_off[i + 1]) e = i;
  half8 hv = {};
  if (e >= 0) {
    int nrem = counts[e] - (gt - tile_off[e]) * BM;
    if (r < nrem) {
      int t = rows_g[p] >> 1;
      const float4* s = reinterpret_cast<const float4*>(x + (size_t)t * C_DIM + kc * 64 + c8 * 8);
      hv = cvt8(s[0], s[1]);
    }
  }
  *reinterpret_cast<half8*>(xg + ((size_t)gt * 16 + kc) * TILE_H + r * 64 + ((c8 ^ (r & 7)) << 3)) = hv;
}

// ---------------- w1 -> tiled fp16
__global__ __launch_bounds__(256) void cvt_w1(
    const float* __restrict__ src, _Float16* __restrict__ dst, int ch, int Fc, int lgFc)
{
  unsigned g = blockIdx.x * 256 + threadIdx.x;
  unsigned row = g >> 7, ccr = g & 127;
  int e = row >> lgFc, frow = row & (Fc - 1);
  int ftl = frow >> 7, r = frow & 127;
  int kc = ccr >> 3, c8 = ccr & 7;
  const float4* s = reinterpret_cast<const float4*>(
      src + ((size_t)e * F_DIM + ch * Fc + frow) * C_DIM + kc * 64 + c8 * 8);
  int nft = Fc >> 7;
  size_t tix = ((size_t)(e * nft + ftl) * 16 + kc);
  *reinterpret_cast<half8*>(dst + tix * TILE_H + r * 64 + ((c8 ^ (r & 7)) << 3)) = cvt8(s[0], s[1]);
}

// ---------------- w2 -> tiled fp16
__global__ __launch_bounds__(256) void cvt_w2(
    const float* __restrict__ src, _Float16* __restrict__ dst, int ch, int Fc, int lgc)
{
  unsigned g = blockIdx.x * 256 + threadIdx.x;
  unsigned row = g >> lgc, ccr = g & ((Fc >> 3) - 1);
  int e = row >> 10, c = row & 1023;
  int ct = c >> 7, r = c & 127;
  int kc = ccr >> 3, c8 = ccr & 7;
  const float4* s = reinterpret_cast<const float4*>(
      src + (size_t)row * F_DIM + ch * Fc + kc * 64 + c8 * 8);
  int nkc = Fc >> 6;
  size_t tix = ((size_t)(e * 8 + ct) * nkc + kc);
  *reinterpret_cast<half8*>(dst + tix * TILE_H + r * 64 + ((c8 ^ (r & 7)) << 3)) = cvt8(s[0], s[1]);
}

// ======== serial single-buffer staging + compute (r3 structure) ========
#define STAGE_TILE(At_, Bt_, kc_)                                                 \
  {                                                                               \
    const _Float16* a_ = (At_) + (size_t)(kc_) * TILE_H + wave * 2048 + lane * 8; \
    const _Float16* b_ = (Bt_) + (size_t)(kc_) * TILE_H + wave * 2048 + lane * 8; \
    _Pragma("unroll")                                                             \
    for (int c_ = 0; c_ < 4; ++c_) {                                              \
      __builtin_amdgcn_global_load_lds((const AS1 void*)(a_ + c_ * 512),          \
          (AS3 void*)(&As[(wave * 4 + c_) * 512]), 16, 0, 0);                     \
      __builtin_amdgcn_global_load_lds((const AS1 void*)(b_ + c_ * 512),          \
          (AS3 void*)(&Bs[(wave * 4 + c_) * 512]), 16, 0, 0);                     \
    }                                                                             \
  }

#define COMPUTE_TILE()                                                            \
  _Pragma("unroll")                                                               \
  for (int kk = 0; kk < BK; kk += 32) {                                           \
    const int klo = kk + (lane >> 4) * 8;                                         \
    half8 aF[4], bF[4];                                                           \
    _Pragma("unroll")                                                             \
    for (int m = 0; m < 4; ++m) {                                                 \
      int r = wr * 64 + m * 16 + (lane & 15);                                     \
      aF[m] = *reinterpret_cast<const half8*>(&As[r * BK + swz(r, klo)]);         \
    }                                                                             \
    _Pragma("unroll")                                                             \
    for (int n = 0; n < 4; ++n) {                                                 \
      int r = wc * 64 + n * 16 + (lane & 15);                                     \
      bF[n] = *reinterpret_cast<const half8*>(&Bs[r * BK + swz(r, klo)]);         \
    }                                                                             \
    _Pragma("unroll")                                                             \
    for (int m = 0; m < 4; ++m)                                                   \
      _Pragma("unroll")                                                           \
      for (int n = 0; n < 4; ++n)                                                 \
        acc[m][n] = __builtin_amdgcn_mfma_f32_16x16x32_f16(aF[m], bF[n], acc[m][n], 0, 0, 0); \
  }

// ---------------- GEMM1: ht[pos, f] = relu(xg[pos] . w1t[e][f] + b1)
__global__ __launch_bounds__(256) void gemm1_kernel(
    const _Float16* __restrict__ xg, const _Float16* __restrict__ w1t,
    const float* __restrict__ b1, const int* __restrict__ counts,
    const int* __restrict__ tile_off, _Float16* __restrict__ ht,
    int ch, int Fc)
{
  const int wgid = xcd_swz(blockIdx.x, gridDim.x);
  const int ft = wgid / MAXT;
  const int gt = wgid - ft * MAXT;
  if (gt >= tile_off[E_NUM]) return;
  int e = 0;
  while (gt >= tile_off[e + 1]) ++e;
  const int nrem = min(counts[e] - (gt - tile_off[e]) * BM, BM);
  const int nft = Fc >> 7;
  const _Float16* At = xg + (size_t)gt * 16 * TILE_H;
  const _Float16* Bt = w1t + (size_t)(e * nft + ft) * 16 * TILE_H;

  __shared__ __align__(16) _Float16 As[TILE_H];
  __shared__ __align__(16) _Float16 Bs[TILE_H];

  const int tid = threadIdx.x;
  const int lane = tid & 63;
  const int wave = tid >> 6;
  const int wr = wave >> 1, wc = wave & 1;

  f32x4 acc[4][4];
#pragma unroll
  for (int m = 0; m < 4; ++m)
#pragma unroll
    for (int n = 0; n < 4; ++n) acc[m][n] = (f32x4){0.f, 0.f, 0.f, 0.f};

  for (int kc = 0; kc < 16; ++kc) {
    STAGE_TILE(At, Bt, kc);
    __syncthreads();
    COMPUTE_TILE();
    __syncthreads();
  }

  const int nkcF = Fc >> 6;
#pragma unroll
  for (int m = 0; m < 4; ++m) {
#pragma unroll
    for (int j = 0; j < 4; ++j) {
      int iloc = wr * 64 + m * 16 + (lane >> 4) * 4 + j;
      if (iloc < nrem) {
#pragma unroll
        for (int n = 0; n < 4; ++n) {
          int fl = ft * BN + wc * 64 + n * 16 + (lane & 15);
          float v = acc[m][n][j] + b1[e * F_DIM + ch * Fc + fl];
          _Float16 h = (_Float16)fmaxf(v, 0.f);
          ht[((size_t)gt * nkcF + (fl >> 6)) * TILE_H + iloc * 64 +
             ((((fl >> 3) & 7) ^ (iloc & 7)) << 3) + (fl & 7)] = h;
        }
      }
    }
  }
}

// ---------------- GEMM2: y[ks][pos][c] (+)= ht[pos] . w2t[e][c]  (fp16, no atomics)
__global__ __launch_bounds__(256) void gemm2_kernel(
    const _Float16* __restrict__ ht, const _Float16* __restrict__ w2t,
    const int* __restrict__ tile_off, _Float16* __restrict__ y,
    int Fc, int kspl, int accum)
{
  const int wgid = xcd_swz(blockIdx.x, gridDim.x);
  const int ctks = wgid / MAXT;
  const int gt = wgid - ctks * MAXT;
  if (gt >= tile_off[E_NUM]) return;
  const int ct = ctks & 7;
  const int ks = ctks >> 3;
  int e = 0;
  while (gt >= tile_off[e + 1]) ++e;
  const int nkc = Fc >> 6;
  const int klen = nkc / kspl;
  const _Float16* At = ht + ((size_t)gt * nkc + ks * klen) * TILE_H;
  const _Float16* Bt = w2t + ((size_t)(e * 8 + ct) * nkc + ks * klen) * TILE_H;

  __shared__ __align__(16) _Float16 As[TILE_H];
  __shared__ __align__(16) _Float16 Bs[TILE_H];

  const int tid = threadIdx.x;
  const int lane = tid & 63;
  const int wave = tid >> 6;
  const int wr = wave >> 1, wc = wave & 1;

  f32x4 acc[4][4];
#pragma unroll
  for (int m = 0; m < 4; ++m)
#pragma unroll
    for (int n = 0; n < 4; ++n) acc[m][n] = (f32x4){0.f, 0.f, 0.f, 0.f};

  for (int kc = 0; kc < klen; ++kc) {
    STAGE_TILE(At, Bt, kc);
    __syncthreads();
    COMPUTE_TILE();
    __syncthreads();
  }

  _Float16* yk = y + ((size_t)(ks * MAXT + gt) * BM) * C_DIM;
#pragma unroll
  for (int m = 0; m < 4; ++m) {
#pragma unroll
    for (int j = 0; j < 4; ++j) {
      int iloc = wr * 64 + m * 16 + (lane >> 4) * 4 + j;
#pragma unroll
      for (int n = 0; n < 4; ++n) {
        int c = ct * BN + wc * 64 + n * 16 + (lane & 15);
        _Float16* p = yk + (size_t)iloc * C_DIM + c;
        float v = acc[m][n][j];
        if (accum) v += (float)*p;
        *p = (_Float16)v;
      }
    }
  }
}

// ---------------- Combine: out[t] = sum_k w_k * (b2[e_k] + sum_ks y[ks][pos_k])
__global__ __launch_bounds__(256) void combine_kernel(
    const _Float16* __restrict__ y, const int* __restrict__ inv,
    const float* __restrict__ top_w, const float* __restrict__ b2,
    float* __restrict__ out, int kspl)
{
  int g = blockIdx.x * 256 + threadIdx.x;
  int t = g >> 7, c8 = (g & 127) << 3;
  float o[8];
#pragma unroll
  for (int i = 0; i < 8; ++i) o[i] = 0.f;
#pragma unroll
  for (int k = 0; k < 2; ++k) {
    int iv = inv[t * 2 + k];
    int e = iv >> 16, pos = iv & 0xffff;
    float w = top_w[t * 2 + k];
    const float4* bb = reinterpret_cast<const float4*>(b2 + e * C_DIM + c8);
    float4 bv0 = bb[0], bv1 = bb[1];
    float s[8] = {bv0.x, bv0.y, bv0.z, bv0.w, bv1.x, bv1.y, bv1.z, bv1.w};
    for (int ks = 0; ks < kspl; ++ks) {
      half8 hv = *reinterpret_cast<const half8*>(
          y + ((size_t)(ks * MAXT * BM + pos)) * C_DIM + c8);
#pragma unroll
      for (int i = 0; i < 8; ++i) s[i] += (float)hv[i];
    }
#pragma unroll
    for (int i = 0; i < 8; ++i) o[i] += w * s[i];
  }
  float4* op = reinterpret_cast<float4*>(out + (size_t)t * C_DIM + c8);
  op[0] = (float4){o[0], o[1], o[2], o[3]};
  op[1] = (float4){o[4], o[5], o[6], o[7]};
}

extern "C" void kernel_launch(void* const* d_in, const int* in_sizes, int n_in,
                              void* d_out, int out_size, void* d_ws, size_t ws_size,
                              hipStream_t stream)
{
  const float* x  = (const float*)d_in[0];
  const float* rw = (const float*)d_in[1];
  const float* w1 = (const float*)d_in[2];
  const float* b1 = (const float*)d_in[3];
  const float* w2 = (const float*)d_in[4];
  const float* b2 = (const float*)d_in[5];
  float* out = (float*)d_out;

  char* ws = (char*)d_ws;
  size_t off = 0;
  auto carve = [&](size_t bytes) -> void* {
    void* p = ws + off;
    off += (bytes + 255) & ~(size_t)255;
    return p;
  };
  int*   top_idx  = (int*)carve((size_t)T_TOK * 2 * sizeof(int));
  float* top_w    = (float*)carve((size_t)T_TOK * 2 * sizeof(float));
  int*   counts   = (int*)carve(E_NUM * sizeof(int));
  int*   tile_off = (int*)carve((E_NUM + 1) * sizeof(int));
  int*   rows_g   = (int*)carve((size_t)NP * sizeof(int));
  int*   inv      = (int*)carve((size_t)T_TOK * 2 * sizeof(int));
  _Float16* xg    = (_Float16*)carve((size_t)MAXT * 16 * TILE_H * sizeof(_Float16));
  _Float16* y     = (_Float16*)carve((size_t)2 * NP * C_DIM * sizeof(_Float16));
  size_t fixed = off;

  int nchunk = 8;
  const int cands[4] = {1, 2, 4, 8};
  for (int ci = 0; ci < 4; ++ci) {
    int n = cands[ci];
    size_t fc = (size_t)(F_DIM / n);
    size_t w1b = ((size_t)E_NUM * fc * C_DIM * 2 + 255) & ~(size_t)255;
    size_t w2b = ((size_t)E_NUM * C_DIM * fc * 2 + 255) & ~(size_t)255;
    size_t htb = ((size_t)MAXT * (fc >> 6) * TILE_H * 2 + 255) & ~(size_t)255;
    if (fixed + w1b + w2b + htb <= ws_size) { nchunk = n; break; }
  }
  const int Fc = F_DIM / nchunk;
  int lgFc = 0; while ((1 << lgFc) < Fc) ++lgFc;
  _Float16* w1t = (_Float16*)carve((size_t)E_NUM * Fc * C_DIM * sizeof(_Float16));
  _Float16* w2t = (_Float16*)carve((size_t)E_NUM * C_DIM * Fc * sizeof(_Float16));
  _Float16* ht  = (_Float16*)carve((size_t)MAXT * (Fc >> 6) * TILE_H * sizeof(_Float16));

  const int kspl = (Fc >= 2048) ? 2 : 1;

  router_kernel<<<T_TOK / 4, 256, 0, stream>>>(x, rw, top_idx, top_w);
  build_lists<<<1, 512, 0, stream>>>(top_idx, rows_g, counts, tile_off, inv);
  gather_x<<<(MAXT * BM * 128) / 256, 256, 0, stream>>>(x, rows_g, counts, tile_off, xg);

  const int cvt_blocks = 4 * Fc;
  for (int ch = 0; ch < nchunk; ++ch) {
    cvt_w1<<<cvt_blocks, 256, 0, stream>>>(w1, w1t, ch, Fc, lgFc);
    cvt_w2<<<cvt_blocks, 256, 0, stream>>>(w2, w2t, ch, Fc, lgFc - 3);
    gemm1_kernel<<<MAXT * (Fc / BN), 256, 0, stream>>>(
        xg, w1t, b1, counts, tile_off, ht, ch, Fc);
    gemm2_kernel<<<MAXT * 8 * kspl, 256, 0, stream>>>(
        ht, w2t, tile_off, y, Fc, kspl, ch != 0);
  }
  combine_kernel<<<(T_TOK * 128) / 256, 256, 0, stream>>>(y, inv, top_w, b2, out, kspl);
}

// Round 6
// 355.157 us; speedup vs baseline: 1.3348x; 1.0755x over previous
//
#include <hip/hip_runtime.h>
#include <hip/hip_fp16.h>

// MoE B=2,N=2048,C=1024,F=4096,E=8,K=2 (T=4096, slots=8192)
// Pre-packed swizzled 128x64 fp16 tiles, linear global_load_lds staging,
// serial 2-barrier K-loop (proven r3/r5). This round: 128x256 tiles with
// 8 waves (512 thr, LDS 48KB, 3 blk/CU) + grouped (8-gt) decode + XCD
// chunking for L2-resident A-strip reuse.

#define T_TOK 4096
#define C_DIM 1024
#define F_DIM 4096
#define E_NUM 8
#define BM 128
#define BN 256
#define BK 64
#define MAXT 72            // max global row-tiles: 8192/128 + 7 pad
#define NP   (MAXT * BM)   // padded positions
#define TILE_H 8192        // halfs per 128x64 tile (16KB)

typedef float f32x4 __attribute__((ext_vector_type(4)));
typedef _Float16 half8 __attribute__((ext_vector_type(8)));

#define AS1 __attribute__((address_space(1)))
#define AS3 __attribute__((address_space(3)))

__device__ __forceinline__ int swz(int r, int ec) { return ec ^ ((r & 7) << 3); }

__device__ __forceinline__ half8 cvt8(float4 f0, float4 f1) {
  half8 hv;
  hv[0] = (_Float16)f0.x; hv[1] = (_Float16)f0.y; hv[2] = (_Float16)f0.z; hv[3] = (_Float16)f0.w;
  hv[4] = (_Float16)f1.x; hv[5] = (_Float16)f1.y; hv[6] = (_Float16)f1.z; hv[7] = (_Float16)f1.w;
  return hv;
}

// bijective XCD chunk swizzle (m204)
__device__ __forceinline__ int xcd_swz(int bid, int nwg) {
  int xcd = bid & 7, rest = bid >> 3;
  int q = nwg >> 3, r = nwg & 7;
  return (xcd < r ? xcd * (q + 1) : r * (q + 1) + (xcd - r) * q) + rest;
}

// ---------------- Router
__global__ __launch_bounds__(256) void router_kernel(
    const float* __restrict__ x, const float* __restrict__ rw,
    int* __restrict__ top_idx, float* __restrict__ top_w)
{
  int t = blockIdx.x * 4 + (threadIdx.x >> 6);
  int lane = threadIdx.x & 63;
  const float* xr = x + (size_t)t * C_DIM;
  float acc[E_NUM];
#pragma unroll
  for (int e = 0; e < E_NUM; ++e) acc[e] = 0.f;
  for (int j = 0; j < C_DIM / 64; ++j) {
    int c = j * 64 + lane;
    float xv = xr[c];
#pragma unroll
    for (int e = 0; e < E_NUM; ++e) acc[e] += xv * rw[e * C_DIM + c];
  }
#pragma unroll
  for (int e = 0; e < E_NUM; ++e) {
    float v = acc[e];
#pragma unroll
    for (int off = 32; off > 0; off >>= 1) v += __shfl_xor(v, off);
    acc[e] = v;
  }
  if (lane == 0) {
    float mx = acc[0];
    for (int e = 1; e < E_NUM; ++e) mx = fmaxf(mx, acc[e]);
    float p[E_NUM]; float Z = 0.f;
    for (int e = 0; e < E_NUM; ++e) { p[e] = expf(acc[e] - mx); Z += p[e]; }
    int b0 = 0;
    for (int e = 1; e < E_NUM; ++e) if (p[e] > p[b0]) b0 = e;
    int b1i = -1; float pb = -1.f;
    for (int e = 0; e < E_NUM; ++e) if (e != b0 && p[e] > pb) { pb = p[e]; b1i = e; }
    float p0 = p[b0] / Z, p1 = pb / Z;
    float s = p0 + p1 + 1e-9f;
    top_idx[t * 2 + 0] = b0;
    top_idx[t * 2 + 1] = b1i;
    top_w[t * 2 + 0] = p0 / s;
    top_w[t * 2 + 1] = p1 / s;
  }
}

// ---------------- Lists (+ inverse map slot -> (expert, padded position))
__global__ void build_lists(const int* __restrict__ top_idx,
                            int* __restrict__ rows_g, int* __restrict__ counts,
                            int* __restrict__ tile_off, int* __restrict__ inv)
{
  int e = threadIdx.x >> 6;
  int lane = threadIdx.x & 63;
  int cnt = 0;
  for (int t0 = 0; t0 < T_TOK; t0 += 64) {
    int t = t0 + lane;
    bool sel = (top_idx[t * 2] == e) || (top_idx[t * 2 + 1] == e);
    cnt += __popcll(__ballot(sel));
  }
  if (lane == 0) counts[e] = cnt;
  __syncthreads();
  if (threadIdx.x == 0) {
    int o = 0;
    for (int i = 0; i < E_NUM; ++i) { tile_off[i] = o; o += (counts[i] + BM - 1) / BM; }
    tile_off[E_NUM] = o;
  }
  __syncthreads();
  int base = tile_off[e] * BM;
  int pos = 0;
  for (int t0 = 0; t0 < T_TOK; t0 += 64) {
    int t = t0 + lane;
    int i0 = top_idx[t * 2], i1 = top_idx[t * 2 + 1];
    bool sel = (i0 == e) || (i1 == e);
    unsigned long long mask = __ballot(sel);
    if (sel) {
      int p = pos + __popcll(mask & ((1ull << lane) - 1ull));
      int slot = t * 2 + ((i0 == e) ? 0 : 1);
      rows_g[base + p] = slot;
      inv[slot] = (e << 16) | (base + p);
    }
    pos += __popcll(mask);
  }
}

// ---------------- Gather x -> tiled swizzled fp16
__global__ __launch_bounds__(256) void gather_x(
    const float* __restrict__ x, const int* __restrict__ rows_g,
    const int* __restrict__ counts, const int* __restrict__ tile_off,
    _Float16* __restrict__ xg)
{
  unsigned g = blockIdx.x * 256 + threadIdx.x;
  unsigned p = g >> 7, ccr = g & 127;
  int gt = p >> 7, r = p & 127;
  int kc = ccr >> 3, c8 = ccr & 7;
  int e = -1;
#pragma unroll
  for (int i = 0; i < E_NUM; ++i)
    if (gt >= tile_off[i] && gt < tile_off[i + 1]) e = i;
  half8 hv = {};
  if (e >= 0) {
    int nrem = counts[e] - (gt - tile_off[e]) * BM;
    if (r < nrem) {
      int t = rows_g[p] >> 1;
      const float4* s = reinterpret_cast<const float4*>(x + (size_t)t * C_DIM + kc * 64 + c8 * 8);
      hv = cvt8(s[0], s[1]);
    }
  }
  *reinterpret_cast<half8*>(xg + ((size_t)gt * 16 + kc) * TILE_H + r * 64 + ((c8 ^ (r & 7)) << 3)) = hv;
}

// ---------------- w1 -> tiled fp16 [e][ftl][kc][128][64] (swizzled)
__global__ __launch_bounds__(256) void cvt_w1(
    const float* __restrict__ src, _Float16* __restrict__ dst, int ch, int Fc, int lgFc)
{
  unsigned g = blockIdx.x * 256 + threadIdx.x;
  unsigned row = g >> 7, ccr = g & 127;
  int e = row >> lgFc, frow = row & (Fc - 1);
  int ftl = frow >> 7, r = frow & 127;
  int kc = ccr >> 3, c8 = ccr & 7;
  const float4* s = reinterpret_cast<const float4*>(
      src + ((size_t)e * F_DIM + ch * Fc + frow) * C_DIM + kc * 64 + c8 * 8);
  int nft = Fc >> 7;
  size_t tix = ((size_t)(e * nft + ftl) * 16 + kc);
  *reinterpret_cast<half8*>(dst + tix * TILE_H + r * 64 + ((c8 ^ (r & 7)) << 3)) = cvt8(s[0], s[1]);
}

// ---------------- w2 -> tiled fp16 [e][ctl][kc][128][64] (swizzled)
__global__ __launch_bounds__(256) void cvt_w2(
    const float* __restrict__ src, _Float16* __restrict__ dst, int ch, int Fc, int lgc)
{
  unsigned g = blockIdx.x * 256 + threadIdx.x;
  unsigned row = g >> lgc, ccr = g & ((Fc >> 3) - 1);
  int e = row >> 10, c = row & 1023;
  int ct = c >> 7, r = c & 127;
  int kc = ccr >> 3, c8 = ccr & 7;
  const float4* s = reinterpret_cast<const float4*>(
      src + (size_t)row * F_DIM + ch * Fc + kc * 64 + c8 * 8);
  int nkc = Fc >> 6;
  size_t tix = ((size_t)(e * 8 + ct) * nkc + kc);
  *reinterpret_cast<half8*>(dst + tix * TILE_H + r * 64 + ((c8 ^ (r & 7)) << 3)) = cvt8(s[0], s[1]);
}

// ======== 512-thread, 128x256-tile staging + compute (serial 2-barrier) ========
// As: 1 tile (16KB). Bs: 2 tiles (32KB). Each thread issues 6 x 16B loads.
#define STAGE_TILE(aSrc_, b0Src_, b1Src_)                                         \
  {                                                                               \
    _Pragma("unroll")                                                             \
    for (int i_ = 0; i_ < 2; ++i_) {                                              \
      int o_ = tid * 8 + i_ * 4096;                                               \
      __builtin_amdgcn_global_load_lds((const AS1 void*)((aSrc_) + o_),           \
          (AS3 void*)(&As[o_]), 16, 0, 0);                                        \
      __builtin_amdgcn_global_load_lds((const AS1 void*)((b0Src_) + o_),          \
          (AS3 void*)(&Bs[o_]), 16, 0, 0);                                        \
      __builtin_amdgcn_global_load_lds((const AS1 void*)((b1Src_) + o_),          \
          (AS3 void*)(&Bs[8192 + o_]), 16, 0, 0);                                 \
    }                                                                             \
  }

#define COMPUTE_TILE()                                                            \
  _Pragma("unroll")                                                               \
  for (int kk = 0; kk < BK; kk += 32) {                                           \
    const int klo = kk + (lane >> 4) * 8;                                         \
    half8 aF[4], bF[4];                                                           \
    _Pragma("unroll")                                                             \
    for (int m = 0; m < 4; ++m) {                                                 \
      int r = wr * 64 + m * 16 + (lane & 15);                                     \
      aF[m] = *reinterpret_cast<const half8*>(&As[r * BK + swz(r, klo)]);         \
    }                                                                             \
    _Pragma("unroll")                                                             \
    for (int n = 0; n < 4; ++n) {                                                 \
      int br = wc * 64 + n * 16 + (lane & 15);                                    \
      bF[n] = *reinterpret_cast<const half8*>(                                    \
          &Bs[(br >> 7) * 8192 + (br & 127) * 64 + swz(br, klo)]);                \
    }                                                                             \
    _Pragma("unroll")                                                             \
    for (int m = 0; m < 4; ++m)                                                   \
      _Pragma("unroll")                                                           \
      for (int n = 0; n < 4; ++n)                                                 \
        acc[m][n] = __builtin_amdgcn_mfma_f32_16x16x32_f16(aF[m], bF[n], acc[m][n], 0, 0, 0); \
  }

// ---------------- GEMM1: ht[pos, f] = relu(xg[pos] . w1t[e][f] + b1)
// grid = MAXT * NFT, decode: 8-gt groups sweeping ft (A strips L2-resident)
__global__ __launch_bounds__(512) void gemm1_kernel(
    const _Float16* __restrict__ xg, const _Float16* __restrict__ w1t,
    const float* __restrict__ b1, const int* __restrict__ counts,
    const int* __restrict__ tile_off, _Float16* __restrict__ ht,
    int ch, int Fc)
{
  const int NFT = Fc / BN;
  const int wgid = xcd_swz(blockIdx.x, gridDim.x);
  const int grp = wgid / (8 * NFT);
  const int rem = wgid - grp * 8 * NFT;
  const int ft = rem >> 3;
  const int gt = grp * 8 + (rem & 7);
  if (gt >= tile_off[E_NUM]) return;
  int e = 0;
  while (gt >= tile_off[e + 1]) ++e;
  const int nrem = min(counts[e] - (gt - tile_off[e]) * BM, BM);
  const int nftl = Fc >> 7;
  const _Float16* At  = xg + (size_t)gt * 16 * TILE_H;
  const _Float16* Bt0 = w1t + (size_t)(e * nftl + 2 * ft) * 16 * TILE_H;
  const _Float16* Bt1 = w1t + (size_t)(e * nftl + 2 * ft + 1) * 16 * TILE_H;

  __shared__ __align__(16) _Float16 As[TILE_H];
  __shared__ __align__(16) _Float16 Bs[2 * TILE_H];

  const int tid = threadIdx.x;
  const int lane = tid & 63;
  const int wave = tid >> 6;
  const int wr = wave >> 2, wc = wave & 3;

  f32x4 acc[4][4];
#pragma unroll
  for (int m = 0; m < 4; ++m)
#pragma unroll
    for (int n = 0; n < 4; ++n) acc[m][n] = (f32x4){0.f, 0.f, 0.f, 0.f};

  for (int kc = 0; kc < 16; ++kc) {
    STAGE_TILE(At + (size_t)kc * TILE_H, Bt0 + (size_t)kc * TILE_H, Bt1 + (size_t)kc * TILE_H);
    __syncthreads();
    COMPUTE_TILE();
    __syncthreads();
  }

  const int nkcF = Fc >> 6;
#pragma unroll
  for (int m = 0; m < 4; ++m) {
#pragma unroll
    for (int j = 0; j < 4; ++j) {
      int iloc = wr * 64 + m * 16 + (lane >> 4) * 4 + j;
      if (iloc < nrem) {
#pragma unroll
        for (int n = 0; n < 4; ++n) {
          int fl = ft * BN + wc * 64 + n * 16 + (lane & 15);
          float v = acc[m][n][j] + b1[e * F_DIM + ch * Fc + fl];
          _Float16 h = (_Float16)fmaxf(v, 0.f);
          ht[((size_t)gt * nkcF + (fl >> 6)) * TILE_H + iloc * 64 +
             ((((fl >> 3) & 7) ^ (iloc & 7)) << 3) + (fl & 7)] = h;
        }
      }
    }
  }
}

// ---------------- GEMM2: y[ks][pos][c] (+)= ht[pos] . w2t[e][c]
// grid = MAXT * 4 * kspl, decode: 8-gt groups sweeping (ct,ks)
__global__ __launch_bounds__(512) void gemm2_kernel(
    const _Float16* __restrict__ ht, const _Float16* __restrict__ w2t,
    const int* __restrict__ tile_off, _Float16* __restrict__ y,
    int Fc, int kspl, int accum)
{
  const int NCMB = 4 * kspl;               // (C/256) * kspl
  const int wgid = xcd_swz(blockIdx.x, gridDim.x);
  const int grp = wgid / (8 * NCMB);
  const int rem = wgid - grp * 8 * NCMB;
  const int cmb = rem >> 3;
  const int gt = grp * 8 + (rem & 7);
  if (gt >= tile_off[E_NUM]) return;
  const int ct = cmb & 3;
  const int ks = cmb >> 2;
  int e = 0;
  while (gt >= tile_off[e + 1]) ++e;
  const int nkc = Fc >> 6;
  const int klen = nkc / kspl;
  const _Float16* At  = ht + ((size_t)gt * nkc + ks * klen) * TILE_H;
  const _Float16* Bt0 = w2t + ((size_t)(e * 8 + 2 * ct) * nkc + ks * klen) * TILE_H;
  const _Float16* Bt1 = w2t + ((size_t)(e * 8 + 2 * ct + 1) * nkc + ks * klen) * TILE_H;

  __shared__ __align__(16) _Float16 As[TILE_H];
  __shared__ __align__(16) _Float16 Bs[2 * TILE_H];

  const int tid = threadIdx.x;
  const int lane = tid & 63;
  const int wave = tid >> 6;
  const int wr = wave >> 2, wc = wave & 3;

  f32x4 acc[4][4];
#pragma unroll
  for (int m = 0; m < 4; ++m)
#pragma unroll
    for (int n = 0; n < 4; ++n) acc[m][n] = (f32x4){0.f, 0.f, 0.f, 0.f};

  for (int kc = 0; kc < klen; ++kc) {
    STAGE_TILE(At + (size_t)kc * TILE_H, Bt0 + (size_t)kc * TILE_H, Bt1 + (size_t)kc * TILE_H);
    __syncthreads();
    COMPUTE_TILE();
    __syncthreads();
  }

  _Float16* yk = y + ((size_t)(ks * MAXT + gt) * BM) * C_DIM;
#pragma unroll
  for (int m = 0; m < 4; ++m) {
#pragma unroll
    for (int j = 0; j < 4; ++j) {
      int iloc = wr * 64 + m * 16 + (lane >> 4) * 4 + j;
#pragma unroll
      for (int n = 0; n < 4; ++n) {
        int c = ct * BN + wc * 64 + n * 16 + (lane & 15);
        _Float16* p = yk + (size_t)iloc * C_DIM + c;
        float v = acc[m][n][j];
        if (accum) v += (float)*p;
        *p = (_Float16)v;
      }
    }
  }
}

// ---------------- Combine: out[t] = sum_k w_k * (b2[e_k] + sum_ks y[ks][pos_k])
__global__ __launch_bounds__(256) void combine_kernel(
    const _Float16* __restrict__ y, const int* __restrict__ inv,
    const float* __restrict__ top_w, const float* __restrict__ b2,
    float* __restrict__ out, int kspl)
{
  int g = blockIdx.x * 256 + threadIdx.x;
  int t = g >> 7, c8 = (g & 127) << 3;
  float o[8];
#pragma unroll
  for (int i = 0; i < 8; ++i) o[i] = 0.f;
#pragma unroll
  for (int k = 0; k < 2; ++k) {
    int iv = inv[t * 2 + k];
    int e = iv >> 16, pos = iv & 0xffff;
    float w = top_w[t * 2 + k];
    const float4* bb = reinterpret_cast<const float4*>(b2 + e * C_DIM + c8);
    float4 bv0 = bb[0], bv1 = bb[1];
    float s[8] = {bv0.x, bv0.y, bv0.z, bv0.w, bv1.x, bv1.y, bv1.z, bv1.w};
    for (int ks = 0; ks < kspl; ++ks) {
      half8 hv = *reinterpret_cast<const half8*>(
          y + ((size_t)(ks * MAXT * BM + pos)) * C_DIM + c8);
#pragma unroll
      for (int i = 0; i < 8; ++i) s[i] += (float)hv[i];
    }
#pragma unroll
    for (int i = 0; i < 8; ++i) o[i] += w * s[i];
  }
  float4* op = reinterpret_cast<float4*>(out + (size_t)t * C_DIM + c8);
  op[0] = (float4){o[0], o[1], o[2], o[3]};
  op[1] = (float4){o[4], o[5], o[6], o[7]};
}

extern "C" void kernel_launch(void* const* d_in, const int* in_sizes, int n_in,
                              void* d_out, int out_size, void* d_ws, size_t ws_size,
                              hipStream_t stream)
{
  const float* x  = (const float*)d_in[0];
  const float* rw = (const float*)d_in[1];
  const float* w1 = (const float*)d_in[2];
  const float* b1 = (const float*)d_in[3];
  const float* w2 = (const float*)d_in[4];
  const float* b2 = (const float*)d_in[5];
  float* out = (float*)d_out;

  char* ws = (char*)d_ws;
  size_t off = 0;
  auto carve = [&](size_t bytes) -> void* {
    void* p = ws + off;
    off += (bytes + 255) & ~(size_t)255;
    return p;
  };
  int*   top_idx  = (int*)carve((size_t)T_TOK * 2 * sizeof(int));
  float* top_w    = (float*)carve((size_t)T_TOK * 2 * sizeof(float));
  int*   counts   = (int*)carve(E_NUM * sizeof(int));
  int*   tile_off = (int*)carve((E_NUM + 1) * sizeof(int));
  int*   rows_g   = (int*)carve((size_t)NP * sizeof(int));
  int*   inv      = (int*)carve((size_t)T_TOK * 2 * sizeof(int));
  _Float16* xg    = (_Float16*)carve((size_t)MAXT * 16 * TILE_H * sizeof(_Float16));
  _Float16* y     = (_Float16*)carve((size_t)2 * NP * C_DIM * sizeof(_Float16));
  size_t fixed = off;

  int nchunk = 8;
  const int cands[4] = {1, 2, 4, 8};
  for (int ci = 0; ci < 4; ++ci) {
    int n = cands[ci];
    size_t fc = (size_t)(F_DIM / n);
    size_t w1b = ((size_t)E_NUM * fc * C_DIM * 2 + 255) & ~(size_t)255;
    size_t w2b = ((size_t)E_NUM * C_DIM * fc * 2 + 255) & ~(size_t)255;
    size_t htb = ((size_t)MAXT * (fc >> 6) * TILE_H * 2 + 255) & ~(size_t)255;
    if (fixed + w1b + w2b + htb <= ws_size) { nchunk = n; break; }
  }
  const int Fc = F_DIM / nchunk;
  int lgFc = 0; while ((1 << lgFc) < Fc) ++lgFc;
  _Float16* w1t = (_Float16*)carve((size_t)E_NUM * Fc * C_DIM * sizeof(_Float16));
  _Float16* w2t = (_Float16*)carve((size_t)E_NUM * C_DIM * Fc * sizeof(_Float16));
  _Float16* ht  = (_Float16*)carve((size_t)MAXT * (Fc >> 6) * TILE_H * sizeof(_Float16));

  const int kspl = (Fc >= 2048) ? 2 : 1;

  router_kernel<<<T_TOK / 4, 256, 0, stream>>>(x, rw, top_idx, top_w);
  build_lists<<<1, 512, 0, stream>>>(top_idx, rows_g, counts, tile_off, inv);
  gather_x<<<(MAXT * BM * 128) / 256, 256, 0, stream>>>(x, rows_g, counts, tile_off, xg);

  const int cvt_blocks = 4 * Fc;
  for (int ch = 0; ch < nchunk; ++ch) {
    cvt_w1<<<cvt_blocks, 256, 0, stream>>>(w1, w1t, ch, Fc, lgFc);
    cvt_w2<<<cvt_blocks, 256, 0, stream>>>(w2, w2t, ch, Fc, lgFc - 3);
    gemm1_kernel<<<MAXT * (Fc / BN), 512, 0, stream>>>(
        xg, w1t, b1, counts, tile_off, ht, ch, Fc);
    gemm2_kernel<<<MAXT * 4 * kspl, 512, 0, stream>>>(
        ht, w2t, tile_off, y, Fc, kspl, ch != 0);
  }
  combine_kernel<<<(T_TOK * 128) / 256, 256, 0, stream>>>(y, inv, top_w, b2, out, kspl);
}